// Round 1
// baseline (75927.368 us; speedup 1.0000x reference)
//
#include <hip/hip_runtime.h>
#include <hip/hip_bf16.h>

#define Bb 32
#define Ss 1024
#define Vv 32000
#define Ee 512
#define Hh 512
#define Ww 128
#define GXC 3072              // 2 dirs * 3H gate columns
#define MR  (Bb * Ss)         // 32768 GEMM rows

typedef short short8  __attribute__((ext_vector_type(8)));
typedef float floatx4 __attribute__((ext_vector_type(4)));
typedef _Float16 f16x2 __attribute__((ext_vector_type(2)));

__device__ inline float dot2f(unsigned w, unsigned h, float acc) {
  return __builtin_amdgcn_fdot2(__builtin_bit_cast(f16x2, w),
                                __builtin_bit_cast(f16x2, h), acc, false);
}
__device__ inline unsigned short bf16bits(float x) {
  return __builtin_bit_cast(unsigned short, __float2bfloat16(x));
}

template<typename T> __device__ inline T gxstore(float v);
template<> __device__ inline float gxstore<float>(float v) { return v; }
template<> __device__ inline __hip_bfloat16 gxstore<__hip_bfloat16>(float v) { return __float2bfloat16(v); }
template<typename T> __device__ inline float gxload(T v);
template<> __device__ inline float gxload<float>(float v) { return v; }
template<> __device__ inline float gxload<__hip_bfloat16>(__hip_bfloat16 v) { return __bfloat162float(v); }

// ---------------- prep kernels ----------------

// emb f32 -> bf16, with padding row 0 zeroed (padding_idx=0 handled once here)
__global__ void prep_emb(const float* __restrict__ emb, unsigned short* __restrict__ out) {
  int i = (blockIdx.x * 256 + threadIdx.x) * 4;   // grid sized exactly: V*E/4 threads
  float4 v = *reinterpret_cast<const float4*>(emb + i);
  bool z = (i < Ee);                               // first row = token 0
  ushort4 o;
  o.x = z ? (unsigned short)0 : bf16bits(v.x);
  o.y = z ? (unsigned short)0 : bf16bits(v.y);
  o.z = z ? (unsigned short)0 : bf16bits(v.z);
  o.w = z ? (unsigned short)0 : bf16bits(v.w);
  *reinterpret_cast<ushort4*>(out + i) = o;
}

// W_ih f/b stacked -> bf16 [3072][512]
__global__ void prep_wih(const float* __restrict__ wf, const float* __restrict__ wb,
                         unsigned short* __restrict__ out) {
  int i = (blockIdx.x * 256 + threadIdx.x) * 4;   // over 3072*512
  const float* src = (i < 1536 * 512) ? (wf + i) : (wb + (i - 1536 * 512));
  float4 v = *reinterpret_cast<const float4*>(src);
  ushort4 o;
  o.x = bf16bits(v.x); o.y = bf16bits(v.y); o.z = bf16bits(v.z); o.w = bf16bits(v.w);
  *reinterpret_cast<ushort4*>(out + i) = o;
}

// W_hh -> f16x2 packed, per-recurrence-thread swizzled layout:
//   out[(dir*384 + j*128 + p)*1024 + tid] = pack(W[g][k], W[g][k+1])
//   where g = j*512 + (tid&511), k = (tid>>9)*256 + 2p
__global__ void prep_whh(const float* __restrict__ wf, const float* __restrict__ wb,
                         unsigned* __restrict__ out) {
  int o = blockIdx.x * 256 + threadIdx.x;  // < 786432
  int tid = o & 1023;
  int u   = o >> 10;                       // dir*384 + i
  int dir = (u >= 384);
  int i   = u - dir * 384;
  int j   = i >> 7;
  int p   = i & 127;
  int g   = (j << 9) | (tid & 511);
  int k   = ((tid >> 9) << 8) | (p << 1);
  const float* W = dir ? wb : wf;
  unsigned lo = __builtin_bit_cast(unsigned short, (_Float16)W[(size_t)g * Hh + k]);
  unsigned hi = __builtin_bit_cast(unsigned short, (_Float16)W[(size_t)g * Hh + k + 1]);
  out[o] = lo | (hi << 16);
}

// ---------------- input-gate GEMM ----------------
// gx[s*32+b][n] = sum_k emb0[seq[b][s]][k] * wihb[n][k]   (bias added in rnn kernel)
// 128x128 tile, BK=64, 4 waves (2x2), mfma 16x16x32 bf16.
template<typename GXT>
__global__ __launch_bounds__(256)
void gx_gemm(const int* __restrict__ seq, const unsigned short* __restrict__ embb,
             const unsigned short* __restrict__ wihb, GXT* __restrict__ gx) {
  __shared__ short As[128][80];   // +16 pad: keeps 16B alignment, breaks worst bank conflicts
  __shared__ short Bs[128][80];
  __shared__ int toks[128];
  const int tid = threadIdx.x;
  const int m0 = blockIdx.y * 128;
  const int n0 = blockIdx.x * 128;
  if (tid < 128) {
    int r = m0 + tid;                       // row = s*32 + b
    toks[tid] = seq[(r & 31) * Ss + (r >> 5)];
  }
  __syncthreads();
  const int lane = tid & 63, wave = tid >> 6;
  const int wm = (wave >> 1) * 64, wn = (wave & 1) * 64;
  floatx4 zero = {0.f, 0.f, 0.f, 0.f};
  floatx4 acc[4][4];
  #pragma unroll
  for (int a = 0; a < 4; ++a)
    #pragma unroll
    for (int c = 0; c < 4; ++c) acc[a][c] = zero;

  for (int k0 = 0; k0 < Ee; k0 += 64) {
    #pragma unroll
    for (int i = 0; i < 4; ++i) {
      int slot = i * 256 + tid;
      int row = slot >> 3, cq = (slot & 7) * 8;
      uint4 va = *reinterpret_cast<const uint4*>(embb + (size_t)toks[row] * Ee + k0 + cq);
      *reinterpret_cast<uint4*>(&As[row][cq]) = va;
      uint4 vb = *reinterpret_cast<const uint4*>(wihb + (size_t)(n0 + row) * Ee + k0 + cq);
      *reinterpret_cast<uint4*>(&Bs[row][cq]) = vb;
    }
    __syncthreads();
    #pragma unroll
    for (int ks = 0; ks < 2; ++ks) {
      short8 af[4], bfr[4];
      #pragma unroll
      for (int mi = 0; mi < 4; ++mi)
        af[mi] = *reinterpret_cast<const short8*>(&As[wm + mi * 16 + (lane & 15)][ks * 32 + (lane >> 4) * 8]);
      #pragma unroll
      for (int ni = 0; ni < 4; ++ni)
        bfr[ni] = *reinterpret_cast<const short8*>(&Bs[wn + ni * 16 + (lane & 15)][ks * 32 + (lane >> 4) * 8]);
      #pragma unroll
      for (int mi = 0; mi < 4; ++mi)
        #pragma unroll
        for (int ni = 0; ni < 4; ++ni)
          acc[mi][ni] = __builtin_amdgcn_mfma_f32_16x16x32_bf16(af[mi], bfr[ni], acc[mi][ni], 0, 0, 0);
    }
    __syncthreads();
  }
  // C layout: col = lane&15, row = (lane>>4)*4 + reg
  #pragma unroll
  for (int mi = 0; mi < 4; ++mi) {
    #pragma unroll
    for (int ni = 0; ni < 4; ++ni) {
      int r0 = m0 + wm + mi * 16 + ((lane >> 4) * 4);
      int c  = n0 + wn + ni * 16 + (lane & 15);
      #pragma unroll
      for (int j = 0; j < 4; ++j)
        gx[(size_t)(r0 + j) * GXC + c] = gxstore<GXT>(acc[mi][ni][j]);
    }
  }
}

// ---------------- recurrence (one block per (dir, batch) chain) ----------------
// 1024 threads: thread owns outputs g0, g0+512, g0+1024 for K-half kh.
// W_hh resident in 384 VGPRs (f16x2). h broadcast through LDS (f16).
// Segment max + final hidden fused.
template<typename GXT>
__global__ __launch_bounds__(1024, 1)
void rnn_kernel(const GXT* __restrict__ gx, const unsigned* __restrict__ whhp,
                const float* __restrict__ bih_f, const float* __restrict__ bhh_f,
                const float* __restrict__ bih_b, const float* __restrict__ bhh_b,
                const int* __restrict__ layout, float* __restrict__ out) {
  __shared__ unsigned hbuf[256];        // 512 f16
  __shared__ float part[3][512];        // K-half partial sums
  __shared__ int lay[Ww + 1];
  const int tid = threadIdx.x;
  const int dir = blockIdx.x >> 5;
  const int b   = blockIdx.x & 31;
  const int g0  = tid & 511;
  const int kh  = tid >> 9;

  unsigned wp[384];
  #pragma unroll
  for (int i = 0; i < 384; ++i)
    wp[i] = whhp[((dir * 384 + i) << 10) | tid];

  float bi0 = 0.f, bi1 = 0.f, bi2 = 0.f, bh0 = 0.f, bh1 = 0.f, bh2 = 0.f;
  if (tid < 512) {
    const float* bi = dir ? bih_b : bih_f;
    const float* bh = dir ? bhh_b : bhh_f;
    bi0 = bi[g0]; bi1 = bi[512 + g0]; bi2 = bi[1024 + g0];
    bh0 = bh[g0]; bh1 = bh[512 + g0]; bh2 = bh[1024 + g0];
  }
  if (tid <= Ww) lay[tid] = layout[b * (Ww + 1) + tid];
  if (tid < 256) hbuf[tid] = 0u;        // h0 = 0
  __syncthreads();

  float h  = 0.f;
  float mx = -3.0e38f;
  int t = dir ? (Ss - 1) : 0;
  const int tstep = dir ? -1 : 1;
  int seg = dir ? (Ww - 1) : 0;

  #pragma unroll 1
  for (int it = 0; it < Ss; ++it, t += tstep) {
    float gr = 0.f, gz = 0.f, gn = 0.f;
    if (tid < 512) {                     // issue gx loads early; consumed after barrier A
      const GXT* gp = gx + (size_t)(t * Bb + b) * GXC + dir * 1536 + g0;
      gr = gxload<GXT>(gp[0]); gz = gxload<GXT>(gp[512]); gn = gxload<GXT>(gp[1024]);
    }
    float s0 = 0.f, s1 = 0.f, s2 = 0.f;
    const uint4* hq4 = reinterpret_cast<const uint4*>(hbuf) + (kh << 5);
    #pragma unroll
    for (int c = 0; c < 32; ++c) {
      uint4 hq = hq4[c];                 // uniform addr -> LDS broadcast, conflict-free
      #pragma unroll
      for (int q = 0; q < 4; ++q) {
        unsigned hp = (&hq.x)[q];
        s0 = dot2f(wp[(c << 2) + q],       hp, s0);
        s1 = dot2f(wp[128 + (c << 2) + q], hp, s1);
        s2 = dot2f(wp[256 + (c << 2) + q], hp, s2);
      }
    }
    if (tid >= 512) { part[0][g0] = s0; part[1][g0] = s1; part[2][g0] = s2; }
    __syncthreads();                     // barrier A: hbuf reads done, partials visible
    if (tid < 512) {
      float rs = gr + bi0 + bh0 + s0 + part[0][g0];
      float zs = gz + bi1 + bh1 + s1 + part[1][g0];
      float nh = bh2 + s2 + part[2][g0];       // gh_n incl. b_hh_n (multiplied by r)
      float r = 1.f / (1.f + __expf(-rs));
      float z = 1.f / (1.f + __expf(-zs));
      float x = gn + bi2 + r * nh;
      x = fminf(fmaxf(x, -15.f), 15.f);
      float e = __expf(2.f * x);
      float n = (e - 1.f) / (e + 1.f);         // tanh
      h = (1.f - z) * n + z * h;
      mx = fmaxf(mx, h);
      reinterpret_cast<_Float16*>(hbuf)[g0] = (_Float16)h;   // publish h'
      bool flush = dir ? (t == lay[seg]) : (t + 1 == lay[seg + 1]);
      if (flush) {
        out[(size_t)(b * Ww + seg) * 1024 + dir * 512 + g0] = mx;
        mx = -3.0e38f;
        seg += tstep;
      }
    }
    __syncthreads();                     // barrier B: h' visible for next step
  }
  if (tid < 512)                          // final hidden [2][B][H]
    out[(size_t)Bb * Ww * 1024 + dir * (Bb * Hh) + b * Hh + g0] = h;
}

// ---------------- host launcher ----------------
extern "C" void kernel_launch(void* const* d_in, const int* in_sizes, int n_in,
                              void* d_out, int out_size, void* d_ws, size_t ws_size,
                              hipStream_t stream) {
  const int*   seq    = (const int*)  d_in[0];
  const int*   layout = (const int*)  d_in[3];
  const float* emb    = (const float*)d_in[4];
  const float* Wih_f  = (const float*)d_in[5];
  const float* Whh_f  = (const float*)d_in[6];
  const float* bih_f  = (const float*)d_in[7];
  const float* bhh_f  = (const float*)d_in[8];
  const float* Wih_b  = (const float*)d_in[9];
  const float* Whh_b  = (const float*)d_in[10];
  const float* bih_b  = (const float*)d_in[11];
  const float* bhh_b  = (const float*)d_in[12];
  float* out = (float*)d_out;

  char* ws = (char*)d_ws;
  unsigned short* embb = (unsigned short*)ws;                       // 32,768,000 B
  unsigned short* wihb = (unsigned short*)(ws + 32768000);          //  3,145,728 B
  unsigned*       whhp = (unsigned*)      (ws + 35913728);          //  3,145,728 B
  void*           gxp  = (void*)          (ws + 39059456);

  const size_t need_f32 = 39059456ULL + (size_t)MR * GXC * 4;       // ~441.7 MB
  const size_t need_b16 = 39059456ULL + (size_t)MR * GXC * 2;       // ~240.4 MB
  if (ws_size < need_b16) return;  // can't run safely; fail validation without corrupting memory

  prep_emb<<<(Vv * Ee) / 4 / 256, 256, 0, stream>>>(emb, embb);
  prep_wih<<<(GXC * Ee) / 4 / 256, 256, 0, stream>>>(Wih_f, Wih_b, wihb);
  prep_whh<<<(2 * 384 * 1024) / 256, 256, 0, stream>>>(Whh_f, Whh_b, whhp);

  if (ws_size >= need_f32) {
    gx_gemm<float><<<dim3(GXC / 128, MR / 128), 256, 0, stream>>>(seq, embb, wihb, (float*)gxp);
    rnn_kernel<float><<<64, 1024, 0, stream>>>((const float*)gxp, whhp,
                                               bih_f, bhh_f, bih_b, bhh_b, layout, out);
  } else {
    gx_gemm<__hip_bfloat16><<<dim3(GXC / 128, MR / 128), 256, 0, stream>>>(seq, embb, wihb, (__hip_bfloat16*)gxp);
    rnn_kernel<__hip_bfloat16><<<64, 1024, 0, stream>>>((const __hip_bfloat16*)gxp, whhp,
                                                        bih_f, bhh_f, bih_b, bhh_b, layout, out);
  }
}

// Round 2
// 33320.688 us; speedup vs baseline: 2.2787x; 2.2787x over previous
//
#include <hip/hip_runtime.h>
#include <hip/hip_bf16.h>

#define Bb 32
#define Ss 1024
#define Vv 32000
#define Ee 512
#define Hh 512
#define Ww 128
#define GXC 3072              // 2 dirs * 3H gate columns
#define MR  (Bb * Ss)         // 32768 GEMM rows

typedef short short8  __attribute__((ext_vector_type(8)));
typedef float floatx4 __attribute__((ext_vector_type(4)));
typedef _Float16 f16x2 __attribute__((ext_vector_type(2)));

__device__ inline float dot2f(unsigned w, unsigned h, float acc) {
  return __builtin_amdgcn_fdot2(__builtin_bit_cast(f16x2, w),
                                __builtin_bit_cast(f16x2, h), acc, false);
}
__device__ inline unsigned short bf16bits(float x) {
  return __builtin_bit_cast(unsigned short, __float2bfloat16(x));
}

template<typename T> __device__ inline T gxstore(float v);
template<> __device__ inline float gxstore<float>(float v) { return v; }
template<> __device__ inline __hip_bfloat16 gxstore<__hip_bfloat16>(float v) { return __float2bfloat16(v); }
template<typename T> __device__ inline float gxload(T v);
template<> __device__ inline float gxload<float>(float v) { return v; }
template<> __device__ inline float gxload<__hip_bfloat16>(__hip_bfloat16 v) { return __bfloat162float(v); }

// ---------------- prep kernels ----------------

// emb f32 -> bf16, with padding row 0 zeroed (padding_idx=0 handled once here)
__global__ void prep_emb(const float* __restrict__ emb, unsigned short* __restrict__ out) {
  int i = (blockIdx.x * 256 + threadIdx.x) * 4;   // grid sized exactly: V*E/4 threads
  float4 v = *reinterpret_cast<const float4*>(emb + i);
  bool z = (i < Ee);                               // first row = token 0
  ushort4 o;
  o.x = z ? (unsigned short)0 : bf16bits(v.x);
  o.y = z ? (unsigned short)0 : bf16bits(v.y);
  o.z = z ? (unsigned short)0 : bf16bits(v.z);
  o.w = z ? (unsigned short)0 : bf16bits(v.w);
  *reinterpret_cast<ushort4*>(out + i) = o;
}

// W_ih f/b stacked -> bf16 [3072][512]
__global__ void prep_wih(const float* __restrict__ wf, const float* __restrict__ wb,
                         unsigned short* __restrict__ out) {
  int i = (blockIdx.x * 256 + threadIdx.x) * 4;   // over 3072*512
  const float* src = (i < 1536 * 512) ? (wf + i) : (wb + (i - 1536 * 512));
  float4 v = *reinterpret_cast<const float4*>(src);
  ushort4 o;
  o.x = bf16bits(v.x); o.y = bf16bits(v.y); o.z = bf16bits(v.z); o.w = bf16bits(v.w);
  *reinterpret_cast<ushort4*>(out + i) = o;
}

// W_hh -> f16x2, laid out so rnn thread `tid` of dir `dir` loads 96 CONTIGUOUS
// uint4 at stride 1024 uint4:  u4[(dir*96 + g*32 + c)*1024 + tid].q
//   = pack(W[grow][k], W[grow][k+1]),  grow = g*512 + (tid&511),
//     p = 4c+q, k = (tid>>9)*256 + 2p
__global__ void prep_whh(const float* __restrict__ wf, const float* __restrict__ wb,
                         unsigned* __restrict__ out) {
  int o = blockIdx.x * 256 + threadIdx.x;  // < 786432 words
  int q    = o & 3;
  int rest = o >> 2;                       // uint4 index
  int tid  = rest & 1023;
  int u    = rest >> 10;                   // 0..191
  int dir  = (u >= 96);
  int jj   = u - dir * 96;
  int g    = jj >> 5;
  int c    = jj & 31;
  int p    = (c << 2) | q;
  int grow = (g << 9) | (tid & 511);
  int k    = ((tid >> 9) << 8) | (p << 1);
  const float* W = dir ? wb : wf;
  unsigned lo = __builtin_bit_cast(unsigned short, (_Float16)W[(size_t)grow * Hh + k]);
  unsigned hi = __builtin_bit_cast(unsigned short, (_Float16)W[(size_t)grow * Hh + k + 1]);
  out[o] = lo | (hi << 16);
}

// ---------------- input-gate GEMM ----------------
template<typename GXT>
__global__ __launch_bounds__(256)
void gx_gemm(const int* __restrict__ seq, const unsigned short* __restrict__ embb,
             const unsigned short* __restrict__ wihb, GXT* __restrict__ gx) {
  __shared__ short As[128][80];
  __shared__ short Bs[128][80];
  __shared__ int toks[128];
  const int tid = threadIdx.x;
  const int m0 = blockIdx.y * 128;
  const int n0 = blockIdx.x * 128;
  if (tid < 128) {
    int r = m0 + tid;                       // row = s*32 + b
    toks[tid] = seq[(r & 31) * Ss + (r >> 5)];
  }
  __syncthreads();
  const int lane = tid & 63, wave = tid >> 6;
  const int wm = (wave >> 1) * 64, wn = (wave & 1) * 64;
  floatx4 zero = {0.f, 0.f, 0.f, 0.f};
  floatx4 acc[4][4];
  #pragma unroll
  for (int a = 0; a < 4; ++a)
    #pragma unroll
    for (int c = 0; c < 4; ++c) acc[a][c] = zero;

  for (int k0 = 0; k0 < Ee; k0 += 64) {
    #pragma unroll
    for (int i = 0; i < 4; ++i) {
      int slot = i * 256 + tid;
      int row = slot >> 3, cq = (slot & 7) * 8;
      uint4 va = *reinterpret_cast<const uint4*>(embb + (size_t)toks[row] * Ee + k0 + cq);
      *reinterpret_cast<uint4*>(&As[row][cq]) = va;
      uint4 vb = *reinterpret_cast<const uint4*>(wihb + (size_t)(n0 + row) * Ee + k0 + cq);
      *reinterpret_cast<uint4*>(&Bs[row][cq]) = vb;
    }
    __syncthreads();
    #pragma unroll
    for (int ks = 0; ks < 2; ++ks) {
      short8 af[4], bfr[4];
      #pragma unroll
      for (int mi = 0; mi < 4; ++mi)
        af[mi] = *reinterpret_cast<const short8*>(&As[wm + mi * 16 + (lane & 15)][ks * 32 + (lane >> 4) * 8]);
      #pragma unroll
      for (int ni = 0; ni < 4; ++ni)
        bfr[ni] = *reinterpret_cast<const short8*>(&Bs[wn + ni * 16 + (lane & 15)][ks * 32 + (lane >> 4) * 8]);
      #pragma unroll
      for (int mi = 0; mi < 4; ++mi)
        #pragma unroll
        for (int ni = 0; ni < 4; ++ni)
          acc[mi][ni] = __builtin_amdgcn_mfma_f32_16x16x32_bf16(af[mi], bfr[ni], acc[mi][ni], 0, 0, 0);
    }
    __syncthreads();
  }
  #pragma unroll
  for (int mi = 0; mi < 4; ++mi) {
    #pragma unroll
    for (int ni = 0; ni < 4; ++ni) {
      int r0 = m0 + wm + mi * 16 + ((lane >> 4) * 4);
      int c  = n0 + wn + ni * 16 + (lane & 15);
      #pragma unroll
      for (int j = 0; j < 4; ++j)
        gx[(size_t)(r0 + j) * GXC + c] = gxstore<GXT>(acc[mi][ni][j]);
    }
  }
}

// ---------------- recurrence ----------------
// 96 NAMED uint4 (384 VGPRs) hold this thread's W_hh slice — no array, no
// dynamic indexing, so mem2reg cannot demote to scratch (R1 post-mortem:
// wp[384] went to local memory -> 104 ms, VALUBusy 1%).

#define DECL96 \
  uint4 W_0,W_1,W_2,W_3,W_4,W_5,W_6,W_7,W_8,W_9,W_10,W_11,W_12,W_13,W_14,W_15, \
  W_16,W_17,W_18,W_19,W_20,W_21,W_22,W_23,W_24,W_25,W_26,W_27,W_28,W_29,W_30,W_31, \
  W_32,W_33,W_34,W_35,W_36,W_37,W_38,W_39,W_40,W_41,W_42,W_43,W_44,W_45,W_46,W_47, \
  W_48,W_49,W_50,W_51,W_52,W_53,W_54,W_55,W_56,W_57,W_58,W_59,W_60,W_61,W_62,W_63, \
  W_64,W_65,W_66,W_67,W_68,W_69,W_70,W_71,W_72,W_73,W_74,W_75,W_76,W_77,W_78,W_79, \
  W_80,W_81,W_82,W_83,W_84,W_85,W_86,W_87,W_88,W_89,W_90,W_91,W_92,W_93,W_94,W_95;

#define LD(n) W_##n = wq[(size_t)(n) * 1024];
#define LD_ALL \
  LD(0)  LD(1)  LD(2)  LD(3)  LD(4)  LD(5)  LD(6)  LD(7)  \
  LD(8)  LD(9)  LD(10) LD(11) LD(12) LD(13) LD(14) LD(15) \
  LD(16) LD(17) LD(18) LD(19) LD(20) LD(21) LD(22) LD(23) \
  LD(24) LD(25) LD(26) LD(27) LD(28) LD(29) LD(30) LD(31) \
  LD(32) LD(33) LD(34) LD(35) LD(36) LD(37) LD(38) LD(39) \
  LD(40) LD(41) LD(42) LD(43) LD(44) LD(45) LD(46) LD(47) \
  LD(48) LD(49) LD(50) LD(51) LD(52) LD(53) LD(54) LD(55) \
  LD(56) LD(57) LD(58) LD(59) LD(60) LD(61) LD(62) LD(63) \
  LD(64) LD(65) LD(66) LD(67) LD(68) LD(69) LD(70) LD(71) \
  LD(72) LD(73) LD(74) LD(75) LD(76) LD(77) LD(78) LD(79) \
  LD(80) LD(81) LD(82) LD(83) LD(84) LD(85) LD(86) LD(87) \
  LD(88) LD(89) LD(90) LD(91) LD(92) LD(93) LD(94) LD(95)

#define DOTC(a, b, e) { uint4 hq = hq4[a]; \
  s0 = dot2f(W_##a.x, hq.x, s0); s0 = dot2f(W_##a.y, hq.y, s0); \
  s0 = dot2f(W_##a.z, hq.z, s0); s0 = dot2f(W_##a.w, hq.w, s0); \
  s1 = dot2f(W_##b.x, hq.x, s1); s1 = dot2f(W_##b.y, hq.y, s1); \
  s1 = dot2f(W_##b.z, hq.z, s1); s1 = dot2f(W_##b.w, hq.w, s1); \
  s2 = dot2f(W_##e.x, hq.x, s2); s2 = dot2f(W_##e.y, hq.y, s2); \
  s2 = dot2f(W_##e.z, hq.z, s2); s2 = dot2f(W_##e.w, hq.w, s2); }

#define DOT_ALL \
  DOTC(0,32,64)  DOTC(1,33,65)  DOTC(2,34,66)  DOTC(3,35,67)  \
  DOTC(4,36,68)  DOTC(5,37,69)  DOTC(6,38,70)  DOTC(7,39,71)  \
  DOTC(8,40,72)  DOTC(9,41,73)  DOTC(10,42,74) DOTC(11,43,75) \
  DOTC(12,44,76) DOTC(13,45,77) DOTC(14,46,78) DOTC(15,47,79) \
  DOTC(16,48,80) DOTC(17,49,81) DOTC(18,50,82) DOTC(19,51,83) \
  DOTC(20,52,84) DOTC(21,53,85) DOTC(22,54,86) DOTC(23,55,87) \
  DOTC(24,56,88) DOTC(25,57,89) DOTC(26,58,90) DOTC(27,59,91) \
  DOTC(28,60,92) DOTC(29,61,93) DOTC(30,62,94) DOTC(31,63,95)

template<typename GXT>
__global__ __launch_bounds__(1024, 1)
void rnn_kernel(const GXT* __restrict__ gx, const unsigned* __restrict__ whhp,
                const float* __restrict__ bih_f, const float* __restrict__ bhh_f,
                const float* __restrict__ bih_b, const float* __restrict__ bhh_b,
                const int* __restrict__ layout, float* __restrict__ out) {
  __shared__ unsigned hbuf[256];        // 512 f16
  __shared__ float part[3][512];        // K-half partial sums
  __shared__ int lay[Ww + 1];
  const int tid = threadIdx.x;
  const int dir = blockIdx.x >> 5;
  const int b   = blockIdx.x & 31;
  const int g0  = tid & 511;
  const int kh  = tid >> 9;

  const uint4* wq = reinterpret_cast<const uint4*>(whhp) + (size_t)dir * 96 * 1024 + tid;
  DECL96
  LD_ALL

  float bi0 = 0.f, bi1 = 0.f, bi2 = 0.f, bh0 = 0.f, bh1 = 0.f, bh2 = 0.f;
  if (tid < 512) {
    const float* bi = dir ? bih_b : bih_f;
    const float* bh = dir ? bhh_b : bhh_f;
    bi0 = bi[g0]; bi1 = bi[512 + g0]; bi2 = bi[1024 + g0];
    bh0 = bh[g0]; bh1 = bh[512 + g0]; bh2 = bh[1024 + g0];
  }
  if (tid <= Ww) lay[tid] = layout[b * (Ww + 1) + tid];
  if (tid < 256) hbuf[tid] = 0u;        // h0 = 0
  __syncthreads();

  float h  = 0.f;
  float mx = -3.0e38f;
  int t = dir ? (Ss - 1) : 0;
  const int tstep = dir ? -1 : 1;
  int seg = dir ? (Ww - 1) : 0;

  #pragma unroll 1
  for (int it = 0; it < Ss; ++it, t += tstep) {
    float gr = 0.f, gz = 0.f, gn = 0.f;
    if (tid < 512) {                     // issue gx loads early; consumed after barrier A
      const GXT* gp = gx + (size_t)(t * Bb + b) * GXC + dir * 1536 + g0;
      gr = gxload<GXT>(gp[0]); gz = gxload<GXT>(gp[512]); gn = gxload<GXT>(gp[1024]);
    }
    float s0 = 0.f, s1 = 0.f, s2 = 0.f;
    const uint4* hq4 = reinterpret_cast<const uint4*>(hbuf) + (kh << 5);
    DOT_ALL
    if (tid >= 512) { part[0][g0] = s0; part[1][g0] = s1; part[2][g0] = s2; }
    __syncthreads();                     // barrier A: hbuf reads done, partials visible
    if (tid < 512) {
      float rs = gr + bi0 + bh0 + s0 + part[0][g0];
      float zs = gz + bi1 + bh1 + s1 + part[1][g0];
      float nh = bh2 + s2 + part[2][g0];       // gh_n incl. b_hh_n (multiplied by r)
      float r = 1.f / (1.f + __expf(-rs));
      float z = 1.f / (1.f + __expf(-zs));
      float x = gn + bi2 + r * nh;
      x = fminf(fmaxf(x, -15.f), 15.f);
      float e = __expf(2.f * x);
      float n = (e - 1.f) / (e + 1.f);         // tanh
      h = (1.f - z) * n + z * h;
      mx = fmaxf(mx, h);
      reinterpret_cast<_Float16*>(hbuf)[g0] = (_Float16)h;   // publish h'
      bool flush = dir ? (t == lay[seg]) : (t + 1 == lay[seg + 1]);
      if (flush) {
        out[(size_t)(b * Ww + seg) * 1024 + dir * 512 + g0] = mx;
        mx = -3.0e38f;
        seg += tstep;
      }
    }
    __syncthreads();                     // barrier B: h' visible for next step
  }
  if (tid < 512)                          // final hidden [2][B][H]
    out[(size_t)Bb * Ww * 1024 + dir * (Bb * Hh) + b * Hh + g0] = h;
}

// ---------------- host launcher ----------------
extern "C" void kernel_launch(void* const* d_in, const int* in_sizes, int n_in,
                              void* d_out, int out_size, void* d_ws, size_t ws_size,
                              hipStream_t stream) {
  const int*   seq    = (const int*)  d_in[0];
  const int*   layout = (const int*)  d_in[3];
  const float* emb    = (const float*)d_in[4];
  const float* Wih_f  = (const float*)d_in[5];
  const float* Whh_f  = (const float*)d_in[6];
  const float* bih_f  = (const float*)d_in[7];
  const float* bhh_f  = (const float*)d_in[8];
  const float* Wih_b  = (const float*)d_in[9];
  const float* Whh_b  = (const float*)d_in[10];
  const float* bih_b  = (const float*)d_in[11];
  const float* bhh_b  = (const float*)d_in[12];
  float* out = (float*)d_out;

  char* ws = (char*)d_ws;
  unsigned short* embb = (unsigned short*)ws;                       // 32,768,000 B
  unsigned short* wihb = (unsigned short*)(ws + 32768000);          //  3,145,728 B
  unsigned*       whhp = (unsigned*)      (ws + 35913728);          //  3,145,728 B
  void*           gxp  = (void*)          (ws + 39059456);

  const size_t need_f32 = 39059456ULL + (size_t)MR * GXC * 4;       // ~441.7 MB
  const size_t need_b16 = 39059456ULL + (size_t)MR * GXC * 2;       // ~240.4 MB
  if (ws_size < need_b16) return;  // can't run safely; fail validation without corrupting memory

  prep_emb<<<(Vv * Ee) / 4 / 256, 256, 0, stream>>>(emb, embb);
  prep_wih<<<(GXC * Ee) / 4 / 256, 256, 0, stream>>>(Wih_f, Wih_b, wihb);
  prep_whh<<<(2 * 384 * 1024) / 256, 256, 0, stream>>>(Whh_f, Whh_b, whhp);

  if (ws_size >= need_f32) {
    gx_gemm<float><<<dim3(GXC / 128, MR / 128), 256, 0, stream>>>(seq, embb, wihb, (float*)gxp);
    rnn_kernel<float><<<64, 1024, 0, stream>>>((const float*)gxp, whhp,
                                               bih_f, bhh_f, bih_b, bhh_b, layout, out);
  } else {
    gx_gemm<__hip_bfloat16><<<dim3(GXC / 128, MR / 128), 256, 0, stream>>>(seq, embb, wihb, (__hip_bfloat16*)gxp);
    rnn_kernel<__hip_bfloat16><<<64, 1024, 0, stream>>>((const __hip_bfloat16*)gxp, whhp,
                                                        bih_f, bhh_f, bih_b, bhh_b, layout, out);
  }
}

// Round 3
// 10146.016 us; speedup vs baseline: 7.4835x; 3.2841x over previous
//
#include <hip/hip_runtime.h>
#include <hip/hip_bf16.h>

#define Bb 32
#define Ss 1024
#define Vv 32000
#define Ee 512
#define Hh 512
#define Ww 128
#define GXC 3072              // 2 dirs * 3H gate columns
#define MR  (Bb * Ss)         // 32768 GEMM rows

typedef short short8  __attribute__((ext_vector_type(8)));
typedef float floatx4 __attribute__((ext_vector_type(4)));
typedef _Float16 f16x2 __attribute__((ext_vector_type(2)));

__device__ inline float dot2f(unsigned w, unsigned h, float acc) {
  return __builtin_amdgcn_fdot2(__builtin_bit_cast(f16x2, w),
                                __builtin_bit_cast(f16x2, h), acc, false);
}
__device__ inline unsigned short bf16bits(float x) {
  return __builtin_bit_cast(unsigned short, __float2bfloat16(x));
}

template<typename T> __device__ inline T gxstore(float v);
template<> __device__ inline float gxstore<float>(float v) { return v; }
template<> __device__ inline __hip_bfloat16 gxstore<__hip_bfloat16>(float v) { return __float2bfloat16(v); }
template<typename T> __device__ inline float gxload(T v);
template<> __device__ inline float gxload<float>(float v) { return v; }
template<> __device__ inline float gxload<__hip_bfloat16>(__hip_bfloat16 v) { return __bfloat162float(v); }

// ---------------- prep kernels ----------------

__global__ void prep_emb(const float* __restrict__ emb, unsigned short* __restrict__ out) {
  int i = (blockIdx.x * 256 + threadIdx.x) * 4;
  float4 v = *reinterpret_cast<const float4*>(emb + i);
  bool z = (i < Ee);                               // first row = token 0 (padding_idx)
  ushort4 o;
  o.x = z ? (unsigned short)0 : bf16bits(v.x);
  o.y = z ? (unsigned short)0 : bf16bits(v.y);
  o.z = z ? (unsigned short)0 : bf16bits(v.z);
  o.w = z ? (unsigned short)0 : bf16bits(v.w);
  *reinterpret_cast<ushort4*>(out + i) = o;
}

__global__ void prep_wih(const float* __restrict__ wf, const float* __restrict__ wb,
                         unsigned short* __restrict__ out) {
  int i = (blockIdx.x * 256 + threadIdx.x) * 4;   // over 3072*512
  const float* src = (i < 1536 * 512) ? (wf + i) : (wb + (i - 1536 * 512));
  float4 v = *reinterpret_cast<const float4*>(src);
  ushort4 o;
  o.x = bf16bits(v.x); o.y = bf16bits(v.y); o.z = bf16bits(v.z); o.w = bf16bits(v.w);
  *reinterpret_cast<ushort4*>(out + i) = o;
}

// W_hh -> f16x2 for the 4-shard rnn:
//   uint4 chunk layout: out_u4[ ((dir*4 + j)*48 + g*16 + i)*512 + tid ]
//   word m of that uint4 = pack(W[row][2kp], W[row][2kp+1])
//   with tid: c=tid>>2 (local hcol), q=tid&3 (K-quarter)
//        row = g*512 + j*128 + c,  kp = q*64 + i*4 + m
__global__ void prep_whh(const float* __restrict__ wf, const float* __restrict__ wb,
                         unsigned* __restrict__ out) {
  int o = blockIdx.x * 256 + threadIdx.x;  // < 786432 words
  int m    = o & 3;
  int u4   = o >> 2;
  int tid  = u4 & 511;
  int rest = u4 >> 9;
  int i    = rest & 15;
  int rest2 = rest >> 4;                   // (dir*4+j)*3 + g, < 24
  int g    = rest2 % 3;
  int rest3 = rest2 / 3;                   // dir*4 + j
  int j    = rest3 & 3;
  int dir  = rest3 >> 2;
  int c    = tid >> 2;
  int q    = tid & 3;
  int row  = g * 512 + j * 128 + c;
  int kp   = q * 64 + i * 4 + m;
  const float* W = dir ? wb : wf;
  unsigned lo = __builtin_bit_cast(unsigned short, (_Float16)W[(size_t)row * Hh + 2 * kp]);
  unsigned hi = __builtin_bit_cast(unsigned short, (_Float16)W[(size_t)row * Hh + 2 * kp + 1]);
  out[o] = lo | (hi << 16);
}

__global__ void zero_flags(unsigned* __restrict__ flags) {
  flags[threadIdx.x] = 0u;                 // <<<1,256>>> : 64 chains x 4 shards
}

// ---------------- input-gate GEMM ----------------
template<typename GXT>
__global__ __launch_bounds__(256)
void gx_gemm(const int* __restrict__ seq, const unsigned short* __restrict__ embb,
             const unsigned short* __restrict__ wihb, GXT* __restrict__ gx) {
  __shared__ short As[128][80];
  __shared__ short Bs[128][80];
  __shared__ int toks[128];
  const int tid = threadIdx.x;
  const int m0 = blockIdx.y * 128;
  const int n0 = blockIdx.x * 128;
  if (tid < 128) {
    int r = m0 + tid;                       // row = s*32 + b
    toks[tid] = seq[(r & 31) * Ss + (r >> 5)];
  }
  __syncthreads();
  const int lane = tid & 63, wave = tid >> 6;
  const int wm = (wave >> 1) * 64, wn = (wave & 1) * 64;
  floatx4 zero = {0.f, 0.f, 0.f, 0.f};
  floatx4 acc[4][4];
  #pragma unroll
  for (int a = 0; a < 4; ++a)
    #pragma unroll
    for (int c = 0; c < 4; ++c) acc[a][c] = zero;

  for (int k0 = 0; k0 < Ee; k0 += 64) {
    #pragma unroll
    for (int i = 0; i < 4; ++i) {
      int slot = i * 256 + tid;
      int row = slot >> 3, cq = (slot & 7) * 8;
      uint4 va = *reinterpret_cast<const uint4*>(embb + (size_t)toks[row] * Ee + k0 + cq);
      *reinterpret_cast<uint4*>(&As[row][cq]) = va;
      uint4 vb = *reinterpret_cast<const uint4*>(wihb + (size_t)(n0 + row) * Ee + k0 + cq);
      *reinterpret_cast<uint4*>(&Bs[row][cq]) = vb;
    }
    __syncthreads();
    #pragma unroll
    for (int ks = 0; ks < 2; ++ks) {
      short8 af[4], bfr[4];
      #pragma unroll
      for (int mi = 0; mi < 4; ++mi)
        af[mi] = *reinterpret_cast<const short8*>(&As[wm + mi * 16 + (lane & 15)][ks * 32 + (lane >> 4) * 8]);
      #pragma unroll
      for (int ni = 0; ni < 4; ++ni)
        bfr[ni] = *reinterpret_cast<const short8*>(&Bs[wn + ni * 16 + (lane & 15)][ks * 32 + (lane >> 4) * 8]);
      #pragma unroll
      for (int mi = 0; mi < 4; ++mi)
        #pragma unroll
        for (int ni = 0; ni < 4; ++ni)
          acc[mi][ni] = __builtin_amdgcn_mfma_f32_16x16x32_bf16(af[mi], bfr[ni], acc[mi][ni], 0, 0, 0);
    }
    __syncthreads();
  }
  #pragma unroll
  for (int mi = 0; mi < 4; ++mi) {
    #pragma unroll
    for (int ni = 0; ni < 4; ++ni) {
      int r0 = m0 + wm + mi * 16 + ((lane >> 4) * 4);
      int c  = n0 + wn + ni * 16 + (lane & 15);
      #pragma unroll
      for (int j = 0; j < 4; ++j)
        gx[(size_t)(r0 + j) * GXC + c] = gxstore<GXT>(acc[mi][ni][j]);
    }
  }
}

// ---------------- recurrence: 4 CUs per chain, flag exchange ----------------
// Block = (chain, shard j). 512 threads, 2 waves/SIMD, 256-VGPR budget.
// Thread: hcol c=tid>>2 (of shard's 128), K-quarter q=tid&3.
// Weights: 48 named uint4 = 192 VGPRs (3 gates x 16 chunks x 4 words x 2 f16).
// h (512 f16) in LDS, parity double-buffered; quarter stride 68 words kills
// bank conflicts (68%32=4 offsets quarters by 4 banks per chunk).

#define H16(M) M(0) M(1) M(2) M(3) M(4) M(5) M(6) M(7) \
               M(8) M(9) M(10) M(11) M(12) M(13) M(14) M(15)

#define WDECL(i) uint4 W0_##i, W1_##i, W2_##i;
#define WLOAD(i) W0_##i = wq[(i) * 512]; \
                 W1_##i = wq[(16 + (i)) * 512]; \
                 W2_##i = wq[(32 + (i)) * 512];
#define CHUNK(i) { uint4 Hq = hq4[i]; \
  s0 = dot2f(W0_##i.x, Hq.x, s0); s0 = dot2f(W0_##i.y, Hq.y, s0); \
  s0 = dot2f(W0_##i.z, Hq.z, s0); s0 = dot2f(W0_##i.w, Hq.w, s0); \
  s1 = dot2f(W1_##i.x, Hq.x, s1); s1 = dot2f(W1_##i.y, Hq.y, s1); \
  s1 = dot2f(W1_##i.z, Hq.z, s1); s1 = dot2f(W1_##i.w, Hq.w, s1); \
  s2 = dot2f(W2_##i.x, Hq.x, s2); s2 = dot2f(W2_##i.y, Hq.y, s2); \
  s2 = dot2f(W2_##i.z, Hq.z, s2); s2 = dot2f(W2_##i.w, Hq.w, s2); }

template<typename GXT>
__global__ __launch_bounds__(512, 2)
void rnn_kernel(const GXT* __restrict__ gx, const unsigned* __restrict__ whh2,
                const float* __restrict__ bih_f, const float* __restrict__ bhh_f,
                const float* __restrict__ bih_b, const float* __restrict__ bhh_b,
                const int* __restrict__ layout, float* __restrict__ out,
                uint4* __restrict__ hx, unsigned* __restrict__ flags) {
  __shared__ unsigned hbufw[544];            // 2 parities x (4 quarters x 68 words)
  __shared__ int lay[Ww + 1];
  const int tid   = threadIdx.x;
  const int j     = blockIdx.x >> 6;         // shard: siblings {c, c+64, c+128, c+192}
  const int chain = blockIdx.x & 63;         //   share XCD under %8 round-robin dispatch
  const int dir   = chain >> 5;
  const int b     = chain & 31;
  const int c     = tid >> 2;                // local hcol 0..127
  const int q     = tid & 3;                 // K-quarter
  const int col   = j * 128 + c;             // global hcol
  const int fidx  = (chain << 2) | j;

  const uint4* wq = reinterpret_cast<const uint4*>(whh2)
                    + (size_t)(dir * 4 + j) * 48 * 512 + tid;
  H16(WDECL)
  H16(WLOAD)

  float bi0 = 0.f, bi1 = 0.f, bi2 = 0.f, bh0 = 0.f, bh1 = 0.f, bh2 = 0.f;
  if (q == 0) {
    const float* bi = dir ? bih_b : bih_f;
    const float* bh = dir ? bhh_b : bhh_f;
    bi0 = bi[col]; bi1 = bi[512 + col]; bi2 = bi[1024 + col];
    bh0 = bh[col]; bh1 = bh[512 + col]; bh2 = bh[1024 + col];
  }
  if (tid <= Ww) lay[tid] = layout[b * (Ww + 1) + tid];
  hbufw[tid] = 0u;
  if (tid < 32) hbufw[512 + tid] = 0u;       // h0 = 0, both parities
  __syncthreads();

  float h = 0.f, mx = -3.0e38f;
  int t = dir ? (Ss - 1) : 0;
  const int tstep = dir ? -1 : 1;
  int seg = dir ? (Ww - 1) : 0;
  int p = 0;

  #pragma unroll 1
  for (int it = 0; it < Ss; ++it, t += tstep) {
    float gr = 0.f, gz = 0.f, gn = 0.f;
    if (q == 0) {                            // issue early; consumed post-dots
      const GXT* gp = gx + (size_t)(t * Bb + b) * GXC + dir * 1536 + col;
      gr = gxload<GXT>(gp[0]); gz = gxload<GXT>(gp[512]); gn = gxload<GXT>(gp[1024]);
    }
    float s0 = 0.f, s1 = 0.f, s2 = 0.f;
    const uint4* hq4 = reinterpret_cast<const uint4*>(hbufw) + p * 68 + q * 17;
    H16(CHUNK)
    { float u;                                // quad butterfly over K-quarters
      u = __shfl_xor(s0, 1); s0 += u; u = __shfl_xor(s0, 2); s0 += u;
      u = __shfl_xor(s1, 1); s1 += u; u = __shfl_xor(s1, 2); s1 += u;
      u = __shfl_xor(s2, 1); s2 += u; u = __shfl_xor(s2, 2); s2 += u; }
    const int P = p ^ 1;
    if (q == 0) {
      float rs = gr + bi0 + bh0 + s0;
      float zs = gz + bi1 + bh1 + s1;
      float nh = bh2 + s2;                   // gh_n incl. b_hh_n (scaled by r)
      float r = 1.f / (1.f + __expf(-rs));
      float z = 1.f / (1.f + __expf(-zs));
      float x = gn + bi2 + r * nh;
      x = fminf(fmaxf(x, -15.f), 15.f);
      float e = __expf(2.f * x);
      float n = (e - 1.f) / (e + 1.f);       // tanh
      h = (1.f - z) * n + z * h;
      mx = fmaxf(mx, h);
      reinterpret_cast<_Float16*>(hbufw)[((P * 272 + j * 68 + (c >> 1)) << 1) | (c & 1)]
          = (_Float16)h;                     // own shard of h_{it+1}
      bool flush = dir ? (t == lay[seg]) : (t + 1 == lay[seg + 1]);
      if (flush) {
        out[(size_t)(b * Ww + seg) * 1024 + dir * 512 + col] = mx;
        mx = -3.0e38f;
        seg += tstep;
      }
    }
    __syncthreads();                         // A: own-quarter h' in LDS
    if (it + 1 < Ss && tid < 64) {           // wave 0: publish + exchange
      if (tid < 16) {                        // publish own 256B shard
        uint4 v = *(reinterpret_cast<const uint4*>(hbufw) + (P * 68 + j * 17 + tid));
        hx[((((size_t)P * 64 + chain) * 4 + j) << 4) + tid] = v;
      }
      asm volatile("s_waitcnt vmcnt(0)" ::: "memory");
      if (tid == 0) {
        __threadfence();
        __hip_atomic_store(&flags[fidx], (unsigned)(it + 1),
                           __ATOMIC_RELEASE, __HIP_MEMORY_SCOPE_AGENT);
      }
      if (tid >= 16 && tid < 28) {           // gather 3 sibling shards
        int s = (tid - 16) >> 2, k = (tid - 16) & 3;
        int sib = s + (s >= j);
        while (__hip_atomic_load(&flags[(chain << 2) | sib],
                                 __ATOMIC_ACQUIRE, __HIP_MEMORY_SCOPE_AGENT)
               <= (unsigned)it) {}
        const uint4* src = hx + ((((size_t)P * 64 + chain) * 4 + sib) << 4) + k * 4;
        uint4 a0 = src[0], a1 = src[1], a2 = src[2], a3 = src[3];
        uint4* dst = reinterpret_cast<uint4*>(hbufw) + (P * 68 + sib * 17 + k * 4);
        dst[0] = a0; dst[1] = a1; dst[2] = a2; dst[3] = a3;
      }
    }
    __syncthreads();                         // C: full h_{it+1} in LDS
    p = P;
  }
  if (q == 0)                                // final hidden [2][B][H]
    out[(size_t)Bb * Ww * 1024 + (size_t)dir * (Bb * Hh) + b * Hh + col] = h;
}

// ---------------- host launcher ----------------
extern "C" void kernel_launch(void* const* d_in, const int* in_sizes, int n_in,
                              void* d_out, int out_size, void* d_ws, size_t ws_size,
                              hipStream_t stream) {
  const int*   seq    = (const int*)  d_in[0];
  const int*   layout = (const int*)  d_in[3];
  const float* emb    = (const float*)d_in[4];
  const float* Wih_f  = (const float*)d_in[5];
  const float* Whh_f  = (const float*)d_in[6];
  const float* bih_f  = (const float*)d_in[7];
  const float* bhh_f  = (const float*)d_in[8];
  const float* Wih_b  = (const float*)d_in[9];
  const float* Whh_b  = (const float*)d_in[10];
  const float* bih_b  = (const float*)d_in[11];
  const float* bhh_b  = (const float*)d_in[12];
  float* out = (float*)d_out;

  char* ws = (char*)d_ws;
  unsigned short* embb  = (unsigned short*)ws;                      // 32,768,000 B
  unsigned short* wihb  = (unsigned short*)(ws + 32768000);         //  3,145,728 B
  unsigned*       whh2  = (unsigned*)      (ws + 35913728);         //  3,145,728 B
  uint4*          hx    = (uint4*)         (ws + 39059456);         //    131,072 B
  unsigned*       flags = (unsigned*)      (ws + 39190528);         //      1,024 B
  void*           gxp   = (void*)          (ws + 39191552);

  const size_t need_f32 = 39191552ULL + (size_t)MR * GXC * 4;       // ~441.8 MB
  const size_t need_b16 = 39191552ULL + (size_t)MR * GXC * 2;       // ~240.5 MB
  if (ws_size < need_b16) return;

  prep_emb<<<(Vv * Ee) / 4 / 256, 256, 0, stream>>>(emb, embb);
  prep_wih<<<(GXC * Ee) / 4 / 256, 256, 0, stream>>>(Wih_f, Wih_b, wihb);
  prep_whh<<<(2 * 4 * 48 * 512 * 4) / 256, 256, 0, stream>>>(Whh_f, Whh_b, whh2);
  zero_flags<<<1, 256, 0, stream>>>(flags);   // stream-ordered: acts as barrier

  if (ws_size >= need_f32) {
    gx_gemm<float><<<dim3(GXC / 128, MR / 128), 256, 0, stream>>>(seq, embb, wihb, (float*)gxp);
    rnn_kernel<float><<<256, 512, 0, stream>>>((const float*)gxp, whh2,
                                               bih_f, bhh_f, bih_b, bhh_b, layout, out, hx, flags);
  } else {
    gx_gemm<__hip_bfloat16><<<dim3(GXC / 128, MR / 128), 256, 0, stream>>>(seq, embb, wihb, (__hip_bfloat16*)gxp);
    rnn_kernel<__hip_bfloat16><<<256, 512, 0, stream>>>((const __hip_bfloat16*)gxp, whh2,
                                                        bih_f, bhh_f, bih_b, bhh_b, layout, out, hx, flags);
  }
}